// Round 7
// baseline (103.289 us; speedup 1.0000x reference)
//
#include <hip/hip_runtime.h>

// MoE all-experts dense MLP, fused bf16-MFMA kernel.
// E=8, D_IN=128, D_HID=256, D_OUT=128, B=65536. Out f32 [B,128].
// R7: BM=128, 4 waves, M=32 rows/wave (full c=64, full n=128 per wave).
// LDS: only W1+b1 record (18KB) double-buffered. W2 fragments read
// global-direct from coalesced W2p packing (L1/L2-hot), issued before the
// stage so counted vmcnt never drains the staging queue. grid 512 ->
// 2 blocks/CU, 8 waves/CU (2/SIMD), target <=256 regs/wave, no spill.

#define E_    8
#define DIN_  128
#define DH_   256
#define DOUT_ 128
#define BM_   128
#define NCHUNK 32
#define REC1  18432   // 16K W1c (swizzled) + 2K b1 rows (64 x 32B)

typedef __attribute__((ext_vector_type(8))) short bf16x8;
typedef __attribute__((ext_vector_type(16))) float f32x16;
typedef __attribute__((ext_vector_type(2))) unsigned int uint2v;

__device__ __forceinline__ unsigned short f2bf(float f) {
  union { float f; unsigned int u; } v; v.f = f;
  unsigned int u = v.u;
  u += 0x7fffu + ((u >> 16) & 1u);
  return (unsigned short)(u >> 16);
}

__device__ __forceinline__ unsigned int cvt_pk_bf16(float lo, float hi) {
  unsigned int r;
  asm("v_cvt_pk_bf16_f32 %0, %1, %2" : "=v"(r) : "v"(lo), "v"(hi));
  return r;
}

__device__ __forceinline__ bf16x8 pack4(unsigned int a, unsigned int b,
                                        unsigned int c, unsigned int d) {
  union { unsigned int u[4]; bf16x8 v; } t;
  t.u[0] = a; t.u[1] = b; t.u[2] = c; t.u[3] = d;
  return t.v;
}

__device__ __forceinline__ void gload_lds16(const void* g, void* l) {
  __builtin_amdgcn_global_load_lds(
      (const __attribute__((address_space(1))) unsigned int*)g,
      (__attribute__((address_space(3))) unsigned int*)l, 16, 0, 0);
}

// ---------------- prep 1: W1 chunk records (proven R5/R6) ----------------
//  [0,16K):   W1c rows c=0..63 x 256B(k): rec[c*256+u] = bf16bytes[c][u^((c&7)<<4)]
//  [16K,18K): b1 rows c=0..63 x 32B: word0 = bf16(b1), rest zero
__global__ __launch_bounds__(256) void prep_w1(
    const float* __restrict__ W1, const float* __restrict__ b1,
    unsigned char* __restrict__ W1r)
{
  __shared__ float T[8192];
  const int t = blockIdx.x;
  const int e = t >> 2, hc = t & 3;
  const int tid = threadIdx.x;
  unsigned char* rec = W1r + (size_t)t * REC1;

  #pragma unroll
  for (int i = 0; i < 32; ++i) {
    int idx = i * 256 + tid;
    int k = idx >> 6, c = idx & 63;
    T[idx] = W1[((size_t)(e * DIN_ + k)) * DH_ + hc * 64 + c];
  }
  __syncthreads();
  #pragma unroll
  for (int j = 0; j < 16; ++j) {
    int widx = j * 256 + tid;
    int c = widx >> 6, uw = (widx & 63) * 4;
    int up = uw ^ ((c & 7) << 4);
    int k0 = up >> 1;
    unsigned int val = (unsigned int)f2bf(T[k0 * 64 + c]) |
                       ((unsigned int)f2bf(T[(k0 + 1) * 64 + c]) << 16);
    *(unsigned int*)(rec + c * 256 + uw) = val;
  }
  if (tid < 64) {
    *(unsigned int*)(rec + 16384 + tid * 32) =
        (unsigned int)f2bf(b1[e * DH_ + hc * 64 + tid]);
    #pragma unroll
    for (int p = 1; p < 8; ++p)
      *(unsigned int*)(rec + 16384 + tid * 32 + p * 4) = 0u;
  }
}

// ---------------- prep 2: W2 coalesced fragment packing (proven R5) ----------
// W2p[t][wh][k2][nf][lane] 16B: lane=(l32,hi): n=nf*32+l32,
// c = hc*64 + wh*32 + k2*16 + hi*8 + j. Frag index i = wh*8 + k2*4 + nf.
__global__ __launch_bounds__(256) void prep_w2p(
    const float* __restrict__ W2, unsigned int* __restrict__ W2p)
{
  const int t = blockIdx.x;
  const int e = t >> 2, hc = t & 3;
  const int tid = threadIdx.x;
  unsigned int* outw = W2p + (size_t)t * 4096;
  #pragma unroll
  for (int j = 0; j < 16; ++j) {
    int w = j * 256 + tid;                 // 0..4095
    int wh = w >> 11, k2 = (w >> 10) & 1, nf = (w >> 8) & 3;
    int lane = (w >> 2) & 63, pr = w & 3;
    int hi = lane >> 5, l32 = lane & 31;
    int n = nf * 32 + l32;
    int c = hc * 64 + wh * 32 + k2 * 16 + hi * 8 + pr * 2;
    unsigned int val =
        (unsigned int)f2bf(W2[((size_t)(e * DH_ + c)) * DOUT_ + n]) |
        ((unsigned int)f2bf(W2[((size_t)(e * DH_ + c + 1)) * DOUT_ + n]) << 16);
    outw[w] = val;
  }
}

// ---------------- main fused kernel ----------------
__global__ __launch_bounds__(256, 2) void moe_main(
    const float* __restrict__ x, const float* __restrict__ wts,
    const float* __restrict__ b2, const unsigned char* __restrict__ W1r,
    const unsigned char* __restrict__ W2p, float* __restrict__ out)
{
  __shared__ __align__(16) unsigned char L[2][REC1];   // 36.9 KB dbuf

  const int tid  = threadIdx.x;
  const int lane = tid & 63;
  const int wv   = tid >> 6;        // 0..3 : m-quarter
  const int l32  = lane & 31;
  const int hi   = lane >> 5;
  const int swz  = (l32 & 7) << 4;
  const long bm  = (long)blockIdx.x * BM_;
  const long m   = bm + wv * 32 + l32;   // this lane's batch row

  auto stage = [&](int t, unsigned char* dst) {
    const unsigned char* src = W1r + (size_t)t * REC1;
    #pragma unroll
    for (int r = 0; r < 4; ++r)
      gload_lds16(src + (r * 256 + tid) * 16, dst + r * 4096 + wv * 1024);
    if (tid < 128)   // waves 0,1 stage the 2KB b1 region
      gload_lds16(src + 16384 + tid * 16, dst + 16384 + wv * 1024);
  };

  stage(0, L[0]);

  // persistent LDS read offsets (chunk loop adds only compile-time imms)
  int p1o[8];
  #pragma unroll
  for (int ks = 0; ks < 8; ++ks)
    p1o[ks] = l32 * 256 + ((ks * 32 + hi * 16) ^ swz);
  const int bo = 16384 + l32 * 32 + hi * 16;

  const bf16x8 ones = pack4(hi ? 0u : 0x3F80u, 0u, 0u, 0u);

  // per-lane expert weights for row m
  float wreg[8];
  {
    float4 a = *(const float4*)(wts + m * E_);
    float4 b = *(const float4*)(wts + m * E_ + 4);
    wreg[0] = a.x; wreg[1] = a.y; wreg[2] = a.z; wreg[3] = a.w;
    wreg[4] = b.x; wreg[5] = b.y; wreg[6] = b.z; wreg[7] = b.w;
  }

  // x fragments (phase-1 B operand): col=m=l32, k = ks*16 + hi*8 + j
  bf16x8 xf[8];
  #pragma unroll
  for (int ks = 0; ks < 8; ++ks) {
    const float* xr = x + m * DIN_ + ks * 16 + hi * 8;
    float4 a = *(const float4*)xr;
    float4 b = *(const float4*)(xr + 4);
    xf[ks] = pack4(cvt_pk_bf16(a.x, a.y), cvt_pk_bf16(a.z, a.w),
                   cvt_pk_bf16(b.x, b.y), cvt_pk_bf16(b.z, b.w));
  }

  f32x16 oacc[4];   // D col=n=nf*32+l32, rows reg-mapped
  #pragma unroll
  for (int nf = 0; nf < 4; ++nf) oacc[nf] = 0.0f;

  auto compute = [&](const unsigned char* Lb, int t, bf16x8* w2f) {
    const int e = t >> 2;
    const float w = wreg[e];
    bf16x8 bfr0 = *(const bf16x8*)(Lb + bo);
    bf16x8 bfr1 = *(const bf16x8*)(Lb + bo + 1024);

    // ---- phase 1: H^T[c][m], c=64, K=128
    f32x16 h0 = 0.0f, h1 = 0.0f;     // cf=0 (c 0..31), cf=1 (c 32..63)
    __builtin_amdgcn_s_setprio(1);
    #pragma unroll
    for (int ks = 0; ks < 8; ++ks) {
      bf16x8 a0 = *(const bf16x8*)(Lb + p1o[ks]);
      bf16x8 a1 = *(const bf16x8*)(Lb + p1o[ks] + 8192);
      h0 = __builtin_amdgcn_mfma_f32_32x32x16_bf16(a0, xf[ks], h0, 0, 0, 0);
      h1 = __builtin_amdgcn_mfma_f32_32x32x16_bf16(a1, xf[ks], h1, 0, 0, 0);
    }
    h0 = __builtin_amdgcn_mfma_f32_32x32x16_bf16(bfr0, ones, h0, 0, 0, 0);
    h1 = __builtin_amdgcn_mfma_f32_32x32x16_bf16(bfr1, ones, h1, 0, 0, 0);
    __builtin_amdgcn_s_setprio(0);

    // ---- relu + fold w; cvt_pk + permlane32_swap -> phase-2 A-frags (T12)
    bf16x8 hfr[4];   // hfr[kk] = c-slice kk*16..kk*16+15
    #pragma unroll
    for (int cf = 0; cf < 2; ++cf) {
      const f32x16& hh = cf ? h1 : h0;
      unsigned int u[8];
      #pragma unroll
      for (int p = 0; p < 8; ++p) {
        float a = fmaxf(hh[2 * p],     0.0f) * w;
        float b = fmaxf(hh[2 * p + 1], 0.0f) * w;
        u[p] = cvt_pk_bf16(a, b);
      }
      uint2v s02 = __builtin_amdgcn_permlane32_swap(u[0], u[2], false, false);
      uint2v s13 = __builtin_amdgcn_permlane32_swap(u[1], u[3], false, false);
      uint2v s46 = __builtin_amdgcn_permlane32_swap(u[4], u[6], false, false);
      uint2v s57 = __builtin_amdgcn_permlane32_swap(u[5], u[7], false, false);
      hfr[2 * cf]     = pack4(s02[0], s13[0], s02[1], s13[1]);
      hfr[2 * cf + 1] = pack4(s46[0], s57[0], s46[1], s57[1]);
    }

    // ---- phase 2: out += H * W2 (K = c = 64)
    __builtin_amdgcn_s_setprio(1);
    #pragma unroll
    for (int kk = 0; kk < 4; ++kk) {
      #pragma unroll
      for (int nf = 0; nf < 4; ++nf) {
        bf16x8 b = w2f[(kk >> 1) * 8 + (kk & 1) * 4 + nf];
        oacc[nf] = __builtin_amdgcn_mfma_f32_32x32x16_bf16(hfr[kk], b, oacc[nf], 0, 0, 0);
      }
    }
    __builtin_amdgcn_s_setprio(0);
  };

  for (int tt = 0; tt < NCHUNK; tt += 2) {
    __syncthreads();                       // L[0] staged; L[1] free
    {
      // W2 frags for chunk tt issued FIRST (older than stage loads -> the
      // phase-2 vmcnt wait leaves the staging queue in flight)
      bf16x8 w2f[16];
      const unsigned char* wb = W2p + (size_t)tt * 16384 + lane * 16;
      #pragma unroll
      for (int i = 0; i < 16; ++i)
        w2f[i] = *(const bf16x8*)(wb + i * 1024);
      stage(tt + 1, L[1]);
      compute(&L[0][0], tt, w2f);
    }
    __syncthreads();                       // L[1] staged; L[0] free
    {
      bf16x8 w2f[16];
      const unsigned char* wb = W2p + (size_t)(tt + 1) * 16384 + lane * 16;
      #pragma unroll
      for (int i = 0; i < 16; ++i)
        w2f[i] = *(const bf16x8*)(wb + i * 1024);
      if (tt + 2 < NCHUNK) stage(tt + 2, L[0]);
      compute(&L[1][0], tt + 1, w2f);
    }
  }

  // ---- epilogue: fold Sigma_e w[m][e]*b2[e][n] via one rank-8 MFMA per nf
  const unsigned int z = 0;
  bf16x8 wfrag = pack4(hi ? z : cvt_pk_bf16(wreg[0], wreg[1]),
                       hi ? z : cvt_pk_bf16(wreg[2], wreg[3]),
                       hi ? z : cvt_pk_bf16(wreg[4], wreg[5]),
                       hi ? z : cvt_pk_bf16(wreg[6], wreg[7]));
  #pragma unroll
  for (int nf = 0; nf < 4; ++nf) {
    const float* bp = b2 + nf * 32 + l32;
    bf16x8 bfrag = pack4(
        hi ? z : cvt_pk_bf16(bp[0 * DOUT_], bp[1 * DOUT_]),
        hi ? z : cvt_pk_bf16(bp[2 * DOUT_], bp[3 * DOUT_]),
        hi ? z : cvt_pk_bf16(bp[4 * DOUT_], bp[5 * DOUT_]),
        hi ? z : cvt_pk_bf16(bp[6 * DOUT_], bp[7 * DOUT_]));
    oacc[nf] = __builtin_amdgcn_mfma_f32_32x32x16_bf16(wfrag, bfrag, oacc[nf], 0, 0, 0);
  }

  // ---- store: out[m][n], n = nf*32+l32, rows reg-mapped
  #pragma unroll
  for (int nf = 0; nf < 4; ++nf) {
    #pragma unroll
    for (int r = 0; r < 16; ++r) {
      const int mloc = (r & 3) + 8 * (r >> 2) + 4 * hi;
      out[(bm + wv * 32 + mloc) * DOUT_ + nf * 32 + l32] = oacc[nf][r];
    }
  }
}

extern "C" void kernel_launch(void* const* d_in, const int* in_sizes, int n_in,
                              void* d_out, int out_size, void* d_ws, size_t ws_size,
                              hipStream_t stream) {
  const float* x   = (const float*)d_in[0];
  const float* wts = (const float*)d_in[1];
  const float* W1  = (const float*)d_in[2];
  const float* b1  = (const float*)d_in[3];
  const float* W2  = (const float*)d_in[4];
  const float* b2  = (const float*)d_in[5];
  float* out = (float*)d_out;

  unsigned char* W1r = (unsigned char*)d_ws;               // 32*18432 = 576 KB
  unsigned char* W2p = W1r + (size_t)NCHUNK * REC1;        // 32*16384 = 512 KB

  prep_w1<<<32, 256, 0, stream>>>(W1, b1, W1r);
  prep_w2p<<<32, 256, 0, stream>>>(W2, (unsigned int*)W2p);
  moe_main<<<65536 / BM_, 256, 0, stream>>>(x, wts, b2, W1r, W2p, out);
}

// Round 8
// 102.729 us; speedup vs baseline: 1.0054x; 1.0054x over previous
//
#include <hip/hip_runtime.h>

// MoE all-experts dense MLP, fused bf16-MFMA kernel.
// E=8, D_IN=128, D_HID=256, D_OUT=128, B=65536. Out f32 [B,128].
// R8: R7 structure (BM=128, 4 waves, M=32/wave, W2 global-direct) +
// counted-vmcnt raw-barrier pipeline (no vmcnt(0) drain in loop) +
// 4-bit W1 LDS swizzle (2-way = free). 2 blocks/CU, 8 waves/CU.

#define E_    8
#define DIN_  128
#define DH_   256
#define DOUT_ 128
#define BM_   128
#define NCHUNK 32
#define REC1  20480   // 16K W1(swz4) + 2K b1 + 2K pad = 5 x 256thr x 16B

typedef __attribute__((ext_vector_type(8))) short bf16x8;
typedef __attribute__((ext_vector_type(16))) float f32x16;
typedef __attribute__((ext_vector_type(2))) unsigned int uint2v;

__device__ __forceinline__ unsigned short f2bf(float f) {
  union { float f; unsigned int u; } v; v.f = f;
  unsigned int u = v.u;
  u += 0x7fffu + ((u >> 16) & 1u);
  return (unsigned short)(u >> 16);
}

__device__ __forceinline__ unsigned int cvt_pk_bf16(float lo, float hi) {
  unsigned int r;
  asm("v_cvt_pk_bf16_f32 %0, %1, %2" : "=v"(r) : "v"(lo), "v"(hi));
  return r;
}

__device__ __forceinline__ bf16x8 pack4(unsigned int a, unsigned int b,
                                        unsigned int c, unsigned int d) {
  union { unsigned int u[4]; bf16x8 v; } t;
  t.u[0] = a; t.u[1] = b; t.u[2] = c; t.u[3] = d;
  return t.v;
}

__device__ __forceinline__ void gload_lds16(const void* g, void* l) {
  __builtin_amdgcn_global_load_lds(
      (const __attribute__((address_space(1))) unsigned int*)g,
      (__attribute__((address_space(3))) unsigned int*)l, 16, 0, 0);
}

// ---------------- prep 1: W1 chunk records, 4-bit swizzle ----------------
//  [0,16K):   W1c rows c=0..63 x 256B(k): rec[c*256+u] = bf16bytes[c][u^((c&15)<<4)]
//  [16K,18K): b1 rows c=0..63 x 32B: word0 = bf16(b1), rest zero. [18K,20K): pad
__global__ __launch_bounds__(256) void prep_w1(
    const float* __restrict__ W1, const float* __restrict__ b1,
    unsigned char* __restrict__ W1r)
{
  __shared__ float T[8192];
  const int t = blockIdx.x;
  const int e = t >> 2, hc = t & 3;
  const int tid = threadIdx.x;
  unsigned char* rec = W1r + (size_t)t * REC1;

  #pragma unroll
  for (int i = 0; i < 32; ++i) {
    int idx = i * 256 + tid;
    int k = idx >> 6, c = idx & 63;
    T[idx] = W1[((size_t)(e * DIN_ + k)) * DH_ + hc * 64 + c];
  }
  __syncthreads();
  #pragma unroll
  for (int j = 0; j < 16; ++j) {
    int widx = j * 256 + tid;
    int c = widx >> 6, uw = (widx & 63) * 4;
    int up = uw ^ ((c & 15) << 4);
    int k0 = up >> 1;
    unsigned int val = (unsigned int)f2bf(T[k0 * 64 + c]) |
                       ((unsigned int)f2bf(T[(k0 + 1) * 64 + c]) << 16);
    *(unsigned int*)(rec + c * 256 + uw) = val;
  }
  if (tid < 64) {
    *(unsigned int*)(rec + 16384 + tid * 32) =
        (unsigned int)f2bf(b1[e * DH_ + hc * 64 + tid]);
    #pragma unroll
    for (int p = 1; p < 8; ++p)
      *(unsigned int*)(rec + 16384 + tid * 32 + p * 4) = 0u;
  }
}

// ---------------- prep 2: W2 coalesced fragment packing (verified R5/R7) ----
// W2p[t][wh][k2][nf][lane] 16B: lane=(l32,hi): n=nf*32+l32,
// c = hc*64 + wh*32 + k2*16 + hi*8 + j. Frag index i = wh*8 + k2*4 + nf.
__global__ __launch_bounds__(256) void prep_w2p(
    const float* __restrict__ W2, unsigned int* __restrict__ W2p)
{
  const int t = blockIdx.x;
  const int e = t >> 2, hc = t & 3;
  const int tid = threadIdx.x;
  unsigned int* outw = W2p + (size_t)t * 4096;
  #pragma unroll
  for (int j = 0; j < 16; ++j) {
    int w = j * 256 + tid;
    int wh = w >> 11, k2 = (w >> 10) & 1, nf = (w >> 8) & 3;
    int lane = (w >> 2) & 63, pr = w & 3;
    int hi = lane >> 5, l32 = lane & 31;
    int n = nf * 32 + l32;
    int c = hc * 64 + wh * 32 + k2 * 16 + hi * 8 + pr * 2;
    unsigned int val =
        (unsigned int)f2bf(W2[((size_t)(e * DH_ + c)) * DOUT_ + n]) |
        ((unsigned int)f2bf(W2[((size_t)(e * DH_ + c + 1)) * DOUT_ + n]) << 16);
    outw[w] = val;
  }
}

// ---------------- main fused kernel ----------------
__global__ __launch_bounds__(256, 2) void moe_main(
    const float* __restrict__ x, const float* __restrict__ wts,
    const float* __restrict__ b2, const unsigned char* __restrict__ W1r,
    const unsigned char* __restrict__ W2p, float* __restrict__ out)
{
  __shared__ __align__(16) unsigned char L[2][REC1];   // 40 KB dbuf

  const int tid  = threadIdx.x;
  const int lane = tid & 63;
  const int wv   = tid >> 6;        // 0..3 : m-quarter
  const int l32  = lane & 31;
  const int hi   = lane >> 5;
  const int swz4 = (l32 & 15) << 4;
  const long bm  = (long)blockIdx.x * BM_;
  const long m   = bm + wv * 32 + l32;

  auto stage = [&](int t, unsigned char* dst) {
    const unsigned char* src = W1r + (size_t)t * REC1;
    #pragma unroll
    for (int r = 0; r < 5; ++r)    // exactly 5 loads/thread, uniform
      gload_lds16(src + (r * 256 + tid) * 16, dst + r * 4096 + wv * 1024);
  };

  stage(0, &L[0][0]);

  int p1o[8];
  #pragma unroll
  for (int ks = 0; ks < 8; ++ks)
    p1o[ks] = l32 * 256 + ((ks * 32 + hi * 16) ^ swz4);
  const int bo = 16384 + l32 * 32 + hi * 16;

  const bf16x8 ones = pack4(hi ? 0u : 0x3F80u, 0u, 0u, 0u);

  float wreg[8];
  {
    float4 a = *(const float4*)(wts + m * E_);
    float4 b = *(const float4*)(wts + m * E_ + 4);
    wreg[0] = a.x; wreg[1] = a.y; wreg[2] = a.z; wreg[3] = a.w;
    wreg[4] = b.x; wreg[5] = b.y; wreg[6] = b.z; wreg[7] = b.w;
  }

  bf16x8 xf[8];
  #pragma unroll
  for (int ks = 0; ks < 8; ++ks) {
    const float* xr = x + m * DIN_ + ks * 16 + hi * 8;
    float4 a = *(const float4*)xr;
    float4 b = *(const float4*)(xr + 4);
    xf[ks] = pack4(cvt_pk_bf16(a.x, a.y), cvt_pk_bf16(a.z, a.w),
                   cvt_pk_bf16(b.x, b.y), cvt_pk_bf16(b.z, b.w));
  }

  f32x16 oacc[4];
  #pragma unroll
  for (int nf = 0; nf < 4; ++nf) oacc[nf] = 0.0f;

  auto compute = [&](const unsigned char* Lb, int t, bf16x8* w2f) {
    const int e = t >> 2;
    const float w = wreg[e];
    bf16x8 bfr0 = *(const bf16x8*)(Lb + bo);
    bf16x8 bfr1 = *(const bf16x8*)(Lb + bo + 1024);

    // phase 1: H^T[c][m], c=64, K=128
    f32x16 h0 = 0.0f, h1 = 0.0f;
    __builtin_amdgcn_s_setprio(1);
    #pragma unroll
    for (int ks = 0; ks < 8; ++ks) {
      bf16x8 a0 = *(const bf16x8*)(Lb + p1o[ks]);
      bf16x8 a1 = *(const bf16x8*)(Lb + p1o[ks] + 8192);
      h0 = __builtin_amdgcn_mfma_f32_32x32x16_bf16(a0, xf[ks], h0, 0, 0, 0);
      h1 = __builtin_amdgcn_mfma_f32_32x32x16_bf16(a1, xf[ks], h1, 0, 0, 0);
    }
    h0 = __builtin_amdgcn_mfma_f32_32x32x16_bf16(bfr0, ones, h0, 0, 0, 0);
    h1 = __builtin_amdgcn_mfma_f32_32x32x16_bf16(bfr1, ones, h1, 0, 0, 0);
    __builtin_amdgcn_s_setprio(0);

    // relu + fold w; cvt_pk + permlane32_swap -> phase-2 A-frags (T12)
    bf16x8 hfr[4];
    #pragma unroll
    for (int cf = 0; cf < 2; ++cf) {
      const f32x16& hh = cf ? h1 : h0;
      unsigned int u[8];
      #pragma unroll
      for (int p = 0; p < 8; ++p) {
        float a = fmaxf(hh[2 * p],     0.0f) * w;
        float b = fmaxf(hh[2 * p + 1], 0.0f) * w;
        u[p] = cvt_pk_bf16(a, b);
      }
      uint2v s02 = __builtin_amdgcn_permlane32_swap(u[0], u[2], false, false);
      uint2v s13 = __builtin_amdgcn_permlane32_swap(u[1], u[3], false, false);
      uint2v s46 = __builtin_amdgcn_permlane32_swap(u[4], u[6], false, false);
      uint2v s57 = __builtin_amdgcn_permlane32_swap(u[5], u[7], false, false);
      hfr[2 * cf]     = pack4(s02[0], s13[0], s02[1], s13[1]);
      hfr[2 * cf + 1] = pack4(s46[0], s57[0], s46[1], s57[1]);
    }

    // phase 2: out += H * W2 (K = c = 64), B-frags from registers
    __builtin_amdgcn_s_setprio(1);
    #pragma unroll
    for (int kk = 0; kk < 4; ++kk) {
      #pragma unroll
      for (int nf = 0; nf < 4; ++nf) {
        bf16x8 b = w2f[(kk >> 1) * 8 + (kk & 1) * 4 + nf];
        oacc[nf] = __builtin_amdgcn_mfma_f32_32x32x16_bf16(hfr[kk], b, oacc[nf], 0, 0, 0);
      }
    }
    __builtin_amdgcn_s_setprio(0);
  };

  int cur = 0;
  for (int t = 0; t < NCHUNK; ++t) {
    __builtin_amdgcn_s_barrier();          // all waves done READING L[cur^1]
    __builtin_amdgcn_sched_barrier(0);
    bf16x8 w2f[16];
    {
      const unsigned char* wb = W2p + (size_t)t * 16384 + lane * 16;
      #pragma unroll
      for (int i = 0; i < 16; ++i)
        w2f[i] = *(const bf16x8*)(wb + i * 1024);
    }
    if (t + 1 < NCHUNK) {
      stage(t + 1, &L[cur ^ 1][0]);
      __builtin_amdgcn_sched_barrier(0);
      // my stage(t) complete: 16 w2f(t) + 5 stage(t+1) newer stay in flight
      asm volatile("s_waitcnt vmcnt(21)" ::: "memory");
    } else {
      __builtin_amdgcn_sched_barrier(0);
      asm volatile("s_waitcnt vmcnt(16)" ::: "memory");
    }
    __builtin_amdgcn_s_barrier();          // all waves' stage(t) complete
    __builtin_amdgcn_sched_barrier(0);
    compute(&L[cur][0], t, w2f);           // w2f waits auto-inserted (vmcnt<=5)
    cur ^= 1;
  }

  // epilogue: fold Sigma_e w[m][e]*b2[e][n] via one rank-8 MFMA per nf
  const unsigned int z = 0;
  bf16x8 wfrag = pack4(hi ? z : cvt_pk_bf16(wreg[0], wreg[1]),
                       hi ? z : cvt_pk_bf16(wreg[2], wreg[3]),
                       hi ? z : cvt_pk_bf16(wreg[4], wreg[5]),
                       hi ? z : cvt_pk_bf16(wreg[6], wreg[7]));
  #pragma unroll
  for (int nf = 0; nf < 4; ++nf) {
    const float* bp = b2 + nf * 32 + l32;
    bf16x8 bfrag = pack4(
        hi ? z : cvt_pk_bf16(bp[0 * DOUT_], bp[1 * DOUT_]),
        hi ? z : cvt_pk_bf16(bp[2 * DOUT_], bp[3 * DOUT_]),
        hi ? z : cvt_pk_bf16(bp[4 * DOUT_], bp[5 * DOUT_]),
        hi ? z : cvt_pk_bf16(bp[6 * DOUT_], bp[7 * DOUT_]));
    oacc[nf] = __builtin_amdgcn_mfma_f32_32x32x16_bf16(wfrag, bfrag, oacc[nf], 0, 0, 0);
  }

  // store: out[m][n], n = nf*32+l32, rows reg-mapped
  #pragma unroll
  for (int nf = 0; nf < 4; ++nf) {
    #pragma unroll
    for (int r = 0; r < 16; ++r) {
      const int mloc = (r & 3) + 8 * (r >> 2) + 4 * hi;
      out[(bm + wv * 32 + mloc) * DOUT_ + nf * 32 + l32] = oacc[nf][r];
    }
  }
}

extern "C" void kernel_launch(void* const* d_in, const int* in_sizes, int n_in,
                              void* d_out, int out_size, void* d_ws, size_t ws_size,
                              hipStream_t stream) {
  const float* x   = (const float*)d_in[0];
  const float* wts = (const float*)d_in[1];
  const float* W1  = (const float*)d_in[2];
  const float* b1  = (const float*)d_in[3];
  const float* W2  = (const float*)d_in[4];
  const float* b2  = (const float*)d_in[5];
  float* out = (float*)d_out;

  unsigned char* W1r = (unsigned char*)d_ws;               // 32*20480 = 640 KB
  unsigned char* W2p = W1r + (size_t)NCHUNK * REC1;        // 32*16384 = 512 KB

  prep_w1<<<32, 256, 0, stream>>>(W1, b1, W1r);
  prep_w2p<<<32, 256, 0, stream>>>(W2, (unsigned int*)W2p);
  moe_main<<<65536 / BM_, 256, 0, stream>>>(x, wts, b2, W1r, W2p, out);
}

// Round 9
// 98.992 us; speedup vs baseline: 1.0434x; 1.0378x over previous
//
#include <hip/hip_runtime.h>

// MoE all-experts dense MLP, fused bf16-MFMA kernel.
// E=8, D_IN=128, D_HID=256, D_OUT=128, B=65536. Out f32 [B,128].
// R9: m201-style phase-interleaved schedule. One 512-thr block (8 waves) per
// CU (BM=256, grid=256), M=32 rows/wave. Per chunk: top {w2f issue, vmcnt(16),
// bar}; C1 {ds ks0-3+b1 issue, stage(t+1) issue, bar, lgkmcnt(0), 10 MFMA};
// C2 {ds ks4-7 issue, bar, lgkmcnt(0), 8 MFMA}; C3 {repack, vmcnt(2),
// 16 MFMA}. Counted vmcnt only — never drained in-loop. setprio on MFMA.

#define E_    8
#define DIN_  128
#define DH_   256
#define DOUT_ 128
#define BM_   256
#define NCHUNK 32
#define REC1  18432   // 16K W1 (swz4) + 2K b1 rows (64 x 32B)

typedef __attribute__((ext_vector_type(8))) short bf16x8;
typedef __attribute__((ext_vector_type(16))) float f32x16;
typedef __attribute__((ext_vector_type(2))) unsigned int uint2v;

__device__ __forceinline__ unsigned short f2bf(float f) {
  union { float f; unsigned int u; } v; v.f = f;
  unsigned int u = v.u;
  u += 0x7fffu + ((u >> 16) & 1u);
  return (unsigned short)(u >> 16);
}

__device__ __forceinline__ unsigned int cvt_pk_bf16(float lo, float hi) {
  unsigned int r;
  asm("v_cvt_pk_bf16_f32 %0, %1, %2" : "=v"(r) : "v"(lo), "v"(hi));
  return r;
}

__device__ __forceinline__ bf16x8 pack4(unsigned int a, unsigned int b,
                                        unsigned int c, unsigned int d) {
  union { unsigned int u[4]; bf16x8 v; } t;
  t.u[0] = a; t.u[1] = b; t.u[2] = c; t.u[3] = d;
  return t.v;
}

__device__ __forceinline__ void gload_lds16(const void* g, void* l) {
  __builtin_amdgcn_global_load_lds(
      (const __attribute__((address_space(1))) unsigned int*)g,
      (__attribute__((address_space(3))) unsigned int*)l, 16, 0, 0);
}

// ---------------- prep 1: W1 chunk records, 4-bit swizzle (proven R8) -------
//  [0,16K):   W1c rows c=0..63 x 256B(k): rec[c*256+u] = bf16bytes[c][u^((c&15)<<4)]
//  [16K,18K): b1 rows c=0..63 x 32B: word0 = bf16(b1), rest zero
__global__ __launch_bounds__(256) void prep_w1(
    const float* __restrict__ W1, const float* __restrict__ b1,
    unsigned char* __restrict__ W1r)
{
  __shared__ float T[8192];
  const int t = blockIdx.x;
  const int e = t >> 2, hc = t & 3;
  const int tid = threadIdx.x;
  unsigned char* rec = W1r + (size_t)t * REC1;

  #pragma unroll
  for (int i = 0; i < 32; ++i) {
    int idx = i * 256 + tid;
    int k = idx >> 6, c = idx & 63;
    T[idx] = W1[((size_t)(e * DIN_ + k)) * DH_ + hc * 64 + c];
  }
  __syncthreads();
  #pragma unroll
  for (int j = 0; j < 16; ++j) {
    int widx = j * 256 + tid;
    int c = widx >> 6, uw = (widx & 63) * 4;
    int up = uw ^ ((c & 15) << 4);
    int k0 = up >> 1;
    unsigned int val = (unsigned int)f2bf(T[k0 * 64 + c]) |
                       ((unsigned int)f2bf(T[(k0 + 1) * 64 + c]) << 16);
    *(unsigned int*)(rec + c * 256 + uw) = val;
  }
  if (tid < 64) {
    *(unsigned int*)(rec + 16384 + tid * 32) =
        (unsigned int)f2bf(b1[e * DH_ + hc * 64 + tid]);
    #pragma unroll
    for (int p = 1; p < 8; ++p)
      *(unsigned int*)(rec + 16384 + tid * 32 + p * 4) = 0u;
  }
}

// ---------------- prep 2: W2 coalesced fragment packing (proven R5/R7/R8) ---
__global__ __launch_bounds__(256) void prep_w2p(
    const float* __restrict__ W2, unsigned int* __restrict__ W2p)
{
  const int t = blockIdx.x;
  const int e = t >> 2, hc = t & 3;
  const int tid = threadIdx.x;
  unsigned int* outw = W2p + (size_t)t * 4096;
  #pragma unroll
  for (int j = 0; j < 16; ++j) {
    int w = j * 256 + tid;
    int wh = w >> 11, k2 = (w >> 10) & 1, nf = (w >> 8) & 3;
    int lane = (w >> 2) & 63, pr = w & 3;
    int hi = lane >> 5, l32 = lane & 31;
    int n = nf * 32 + l32;
    int c = hc * 64 + wh * 32 + k2 * 16 + hi * 8 + pr * 2;
    unsigned int val =
        (unsigned int)f2bf(W2[((size_t)(e * DH_ + c)) * DOUT_ + n]) |
        ((unsigned int)f2bf(W2[((size_t)(e * DH_ + c + 1)) * DOUT_ + n]) << 16);
    outw[w] = val;
  }
}

// ---------------- main fused kernel ----------------
__global__ __launch_bounds__(512, 1) void moe_main(
    const float* __restrict__ x, const float* __restrict__ wts,
    const float* __restrict__ b2, const unsigned char* __restrict__ W1r,
    const unsigned char* __restrict__ W2p, float* __restrict__ out)
{
  __shared__ __align__(16) unsigned char L[2][REC1];   // 36.9 KB dbuf

  const int tid  = threadIdx.x;
  const int lane = tid & 63;
  const int wv   = tid >> 6;        // 0..7 : m-32-tile
  const int l32  = lane & 31;
  const int hi   = lane >> 5;
  const int swz4 = (l32 & 15) << 4;
  const long bm  = (long)blockIdx.x * BM_;
  const long m   = bm + wv * 32 + l32;

  auto stage = [&](int t, unsigned char* dst) {
    const unsigned char* src = W1r + (size_t)t * REC1;
    #pragma unroll
    for (int r = 0; r < 2; ++r)
      gload_lds16(src + (r * 512 + tid) * 16, dst + r * 8192 + wv * 1024);
    if (tid < 128)   // waves 0,1 stage the 2KB b1 region
      gload_lds16(src + 16384 + tid * 16, dst + 16384 + wv * 1024);
  };

  stage(0, &L[0][0]);

  int p1o[8];
  #pragma unroll
  for (int ks = 0; ks < 8; ++ks)
    p1o[ks] = l32 * 256 + ((ks * 32 + hi * 16) ^ swz4);
  const int bo = 16384 + l32 * 32 + hi * 16;

  const bf16x8 ones = pack4(hi ? 0u : 0x3F80u, 0u, 0u, 0u);

  float wreg[8];
  {
    float4 a = *(const float4*)(wts + m * E_);
    float4 b = *(const float4*)(wts + m * E_ + 4);
    wreg[0] = a.x; wreg[1] = a.y; wreg[2] = a.z; wreg[3] = a.w;
    wreg[4] = b.x; wreg[5] = b.y; wreg[6] = b.z; wreg[7] = b.w;
  }

  bf16x8 xf[8];
  #pragma unroll
  for (int ks = 0; ks < 8; ++ks) {
    const float* xr = x + m * DIN_ + ks * 16 + hi * 8;
    float4 a = *(const float4*)xr;
    float4 b = *(const float4*)(xr + 4);
    xf[ks] = pack4(cvt_pk_bf16(a.x, a.y), cvt_pk_bf16(a.z, a.w),
                   cvt_pk_bf16(b.x, b.y), cvt_pk_bf16(b.z, b.w));
  }

  f32x16 oacc[4];
  #pragma unroll
  for (int nf = 0; nf < 4; ++nf) oacc[nf] = 0.0f;

  for (int t = 0; t < NCHUNK; ++t) {
    const unsigned char* Lb = &L[t & 1][0];
    unsigned char* Ln = &L[(t + 1) & 1][0];

    // ---- top: issue w2f(t); stage(t) is 16-deep in the queue -> vmcnt(16)
    bf16x8 w2f[16];
    {
      const unsigned char* wb = W2p + (size_t)t * 16384 + lane * 16;
      #pragma unroll
      for (int i = 0; i < 16; ++i)
        w2f[i] = *(const bf16x8*)(wb + i * 1024);
    }
    __builtin_amdgcn_sched_barrier(0);
    asm volatile("s_waitcnt vmcnt(16)" ::: "memory");   // stage(t) landed
    __builtin_amdgcn_sched_barrier(0);
    __builtin_amdgcn_s_barrier();                       // L[t&1] valid for all
    __builtin_amdgcn_sched_barrier(0);

    // ---- C1: issue ds_reads ks0-3 + b1; issue stage(t+1); bar; wait; MFMA
    bf16x8 a0[4], a1[4];
    #pragma unroll
    for (int ks = 0; ks < 4; ++ks) {
      a0[ks] = *(const bf16x8*)(Lb + p1o[ks]);
      a1[ks] = *(const bf16x8*)(Lb + p1o[ks] + 8192);
    }
    bf16x8 bfr0 = *(const bf16x8*)(Lb + bo);
    bf16x8 bfr1 = *(const bf16x8*)(Lb + bo + 1024);
    if (t + 1 < NCHUNK) stage(t + 1, Ln);
    __builtin_amdgcn_sched_barrier(0);
    __builtin_amdgcn_s_barrier();
    asm volatile("s_waitcnt lgkmcnt(0)" ::: "memory");
    __builtin_amdgcn_sched_barrier(0);

    f32x16 h0 = 0.0f, h1 = 0.0f;
    __builtin_amdgcn_s_setprio(1);
    h0 = __builtin_amdgcn_mfma_f32_32x32x16_bf16(bfr0, ones, h0, 0, 0, 0);
    h1 = __builtin_amdgcn_mfma_f32_32x32x16_bf16(bfr1, ones, h1, 0, 0, 0);
    #pragma unroll
    for (int ks = 0; ks < 4; ++ks) {
      h0 = __builtin_amdgcn_mfma_f32_32x32x16_bf16(a0[ks], xf[ks], h0, 0, 0, 0);
      h1 = __builtin_amdgcn_mfma_f32_32x32x16_bf16(a1[ks], xf[ks], h1, 0, 0, 0);
    }
    __builtin_amdgcn_s_setprio(0);
    __builtin_amdgcn_sched_barrier(0);

    // ---- C2: issue ds_reads ks4-7; bar; wait; MFMA
    bf16x8 b0[4], b1v[4];
    #pragma unroll
    for (int ks = 0; ks < 4; ++ks) {
      b0[ks] = *(const bf16x8*)(Lb + p1o[ks + 4]);
      b1v[ks] = *(const bf16x8*)(Lb + p1o[ks + 4] + 8192);
    }
    __builtin_amdgcn_sched_barrier(0);
    __builtin_amdgcn_s_barrier();
    asm volatile("s_waitcnt lgkmcnt(0)" ::: "memory");
    __builtin_amdgcn_sched_barrier(0);
    __builtin_amdgcn_s_setprio(1);
    #pragma unroll
    for (int ks = 0; ks < 4; ++ks) {
      h0 = __builtin_amdgcn_mfma_f32_32x32x16_bf16(b0[ks], xf[ks + 4], h0, 0, 0, 0);
      h1 = __builtin_amdgcn_mfma_f32_32x32x16_bf16(b1v[ks], xf[ks + 4], h1, 0, 0, 0);
    }
    __builtin_amdgcn_s_setprio(0);
    __builtin_amdgcn_sched_barrier(0);

    // ---- C3: repack (VALU, overlaps other waves' C1/C2 MFMA) -> phase-2
    const float w = wreg[t >> 2];
    bf16x8 hfr[4];
    #pragma unroll
    for (int cf = 0; cf < 2; ++cf) {
      const f32x16& hh = cf ? h1 : h0;
      unsigned int u[8];
      #pragma unroll
      for (int p = 0; p < 8; ++p) {
        float a = fmaxf(hh[2 * p],     0.0f) * w;
        float b = fmaxf(hh[2 * p + 1], 0.0f) * w;
        u[p] = cvt_pk_bf16(a, b);
      }
      uint2v s02 = __builtin_amdgcn_permlane32_swap(u[0], u[2], false, false);
      uint2v s13 = __builtin_amdgcn_permlane32_swap(u[1], u[3], false, false);
      uint2v s46 = __builtin_amdgcn_permlane32_swap(u[4], u[6], false, false);
      uint2v s57 = __builtin_amdgcn_permlane32_swap(u[5], u[7], false, false);
      hfr[2 * cf]     = pack4(s02[0], s13[0], s02[1], s13[1]);
      hfr[2 * cf + 1] = pack4(s46[0], s57[0], s46[1], s57[1]);
    }
    // w2f(t) complete; only stage(t+1) (<=2 per wave, min-S) may remain
    if (t + 1 < NCHUNK) {
      asm volatile("s_waitcnt vmcnt(2)" ::: "memory");
    } else {
      asm volatile("s_waitcnt vmcnt(0)" ::: "memory");
    }
    __builtin_amdgcn_sched_barrier(0);
    __builtin_amdgcn_s_setprio(1);
    #pragma unroll
    for (int kk = 0; kk < 4; ++kk) {
      #pragma unroll
      for (int nf = 0; nf < 4; ++nf) {
        bf16x8 b = w2f[(kk >> 1) * 8 + (kk & 1) * 4 + nf];
        oacc[nf] = __builtin_amdgcn_mfma_f32_32x32x16_bf16(hfr[kk], b, oacc[nf], 0, 0, 0);
      }
    }
    __builtin_amdgcn_s_setprio(0);
    __builtin_amdgcn_sched_barrier(0);
  }

  // ---- epilogue: fold Sigma_e w[m][e]*b2[e][n] via one rank-8 MFMA per nf
  const unsigned int z = 0;
  bf16x8 wfrag = pack4(hi ? z : cvt_pk_bf16(wreg[0], wreg[1]),
                       hi ? z : cvt_pk_bf16(wreg[2], wreg[3]),
                       hi ? z : cvt_pk_bf16(wreg[4], wreg[5]),
                       hi ? z : cvt_pk_bf16(wreg[6], wreg[7]));
  #pragma unroll
  for (int nf = 0; nf < 4; ++nf) {
    const float* bp = b2 + nf * 32 + l32;
    bf16x8 bfrag = pack4(
        hi ? z : cvt_pk_bf16(bp[0 * DOUT_], bp[1 * DOUT_]),
        hi ? z : cvt_pk_bf16(bp[2 * DOUT_], bp[3 * DOUT_]),
        hi ? z : cvt_pk_bf16(bp[4 * DOUT_], bp[5 * DOUT_]),
        hi ? z : cvt_pk_bf16(bp[6 * DOUT_], bp[7 * DOUT_]));
    oacc[nf] = __builtin_amdgcn_mfma_f32_32x32x16_bf16(wfrag, bfrag, oacc[nf], 0, 0, 0);
  }

  // ---- store: out[m][n], n = nf*32+l32, rows reg-mapped
  #pragma unroll
  for (int nf = 0; nf < 4; ++nf) {
    #pragma unroll
    for (int r = 0; r < 16; ++r) {
      const int mloc = (r & 3) + 8 * (r >> 2) + 4 * hi;
      out[(bm + wv * 32 + mloc) * DOUT_ + nf * 32 + l32] = oacc[nf][r];
    }
  }
}

extern "C" void kernel_launch(void* const* d_in, const int* in_sizes, int n_in,
                              void* d_out, int out_size, void* d_ws, size_t ws_size,
                              hipStream_t stream) {
  const float* x   = (const float*)d_in[0];
  const float* wts = (const float*)d_in[1];
  const float* W1  = (const float*)d_in[2];
  const float* b1  = (const float*)d_in[3];
  const float* W2  = (const float*)d_in[4];
  const float* b2  = (const float*)d_in[5];
  float* out = (float*)d_out;

  unsigned char* W1r = (unsigned char*)d_ws;               // 32*18432 = 576 KB
  unsigned char* W2p = W1r + (size_t)NCHUNK * REC1;        // 32*16384 = 512 KB

  prep_w1<<<32, 256, 0, stream>>>(W1, b1, W1r);
  prep_w2p<<<32, 256, 0, stream>>>(W2, (unsigned int*)W2p);
  moe_main<<<65536 / BM_, 512, 0, stream>>>(x, wts, b2, W1r, W2p, out);
}